// Round 7
// baseline (722.623 us; speedup 1.0000x reference)
//
#include <hip/hip_runtime.h>
#include <hip/hip_bf16.h>

#define Dh 2048
#define Bh 4
#define Sh 2048
#define NROW 8192          // B*S
#define HALF 1024
#define INV_SQRT_D 0.022097086912079608f
#define LNEPS 1e-5f

typedef __hip_bfloat16 bf16;
typedef short short8 __attribute__((ext_vector_type(8)));
typedef float f32x4 __attribute__((ext_vector_type(4)));

__device__ inline float warp_sum(float x) {
#pragma unroll
  for (int o = 32; o > 0; o >>= 1) x += __shfl_down(x, o);
  return x;
}
__device__ inline float warp_max(float x) {
#pragma unroll
  for (int o = 32; o > 0; o >>= 1) x = fmaxf(x, __shfl_down(x, o));
  return x;
}
__device__ inline float block_sum(float x, float* sm4) {
  x = warp_sum(x);
  int w = threadIdx.x >> 6;
  if ((threadIdx.x & 63) == 0) sm4[w] = x;
  __syncthreads();
  float r = sm4[0] + sm4[1] + sm4[2] + sm4[3];
  __syncthreads();
  return r;
}
__device__ inline float block_max(float x, float* sm4) {
  x = warp_max(x);
  int w = threadIdx.x >> 6;
  if ((threadIdx.x & 63) == 0) sm4[w] = x;
  __syncthreads();
  float r = fmaxf(fmaxf(sm4[0], sm4[1]), fmaxf(sm4[2], sm4[3]));
  __syncthreads();
  return r;
}

// async global->LDS, 16B per lane; LDS dest is wave-uniform base + lane*16
__device__ inline void gload_lds16(const void* g, void* lds) {
  __builtin_amdgcn_global_load_lds(
      (const __attribute__((address_space(1))) unsigned int*)(unsigned long long)g,
      (__attribute__((address_space(3))) unsigned int*)(unsigned long long)lds,
      16, 0, 0);
}

// ---------------------------------------------------------------------------
// Phase-pipelined MFMA bf16 GEMM: C[M,N] = A[M,K] @ B[N,K]^T.
// 256x256 tile, BK=32, 8 waves (2Mx4N), per-wave 128x64 output.
// LDS 96KB: 3 rotating regions x (A 16KB + B 16KB), region = t % 3.
//
// R7 SCHEDULE: one-phase-ahead register prefetch so the LDS pipe and the
// MFMA pipes overlap (R3-R6 all alternated them; MfmaUtil pinned at ~41%).
// Per tile t, two phases; MFMA clusters consume frags loaded one phase ago:
//  ph0: read a4..7(t) | stage(t+2,h0) | MFMA a0..3 x Bcur |
//       lgkmcnt(0); vmcnt(2|0); s_barrier        <- drains stage(t+1)
//  ph1: read a0..3(t+1)+Bnxt(t+1) | stage(t+2,h1) | MFMA a4..7 x Bcur |
//       lgkmcnt(0); s_barrier
// B frags double-banked (be/bo, unrolled 2 tiles) to avoid copies.
// Counting (steady): entry outstanding = 4 (tile t+1's stages, issued in
// t-1); ph0 +2 -> 6; vmcnt(2) drains t+1's 4, leaves h0's 2; ph1 +2 -> 4.
// Race ledger: reads of region t+1 (ph1 of tile t) happen after mid-tile
// vmcnt+barrier which drains stage(t+1) [issued tile t-1]. stage(t+2)
// targets region (t+2)%3 whose last reads (frags of t-1) completed before
// the end-of-(t-1) barrier (each phase ends lgkmcnt(0) before s_barrier).
// T2 swizzle (R4, zero conflicts measured): LDS row R granule slot s holds
// global granule s ^ ((R>>1)&3); staging pre-swizzles the GLOBAL source
// (G = (l&3)^((l>>3)&3)), frag reads use slot (l>>4)^((l>>1)&3).
// nt is even (>=8) for every launch in this file.
// MODE 0: C f32 = acc                                        (prc)
// MODE 1: C bf16 = silu(acc + e0[z*D+c]) * e1[(z*4+b)*D+c]   (qkv)
// MODE 2: C f32 = acc * INV_SQRT_D, skip blocks above diagonal (QK^T)
// MODE 3: C bf16 = acc, K bounded at bm0+256 (causal PV)
// MODE 4: C f32 = e2[r*N+c] + e1[b*D+c] * silu(acc + e0[c])  (o-proj+resid)
// ---------------------------------------------------------------------------
template <int MODE>
__global__ __launch_bounds__(512) void pgemm(
    const bf16* __restrict__ Aall, const bf16* __restrict__ Ball,
    void* __restrict__ Call, int N, int K, int lda, int ldb,
    long sAz, long sBz, long sCz,
    const float* __restrict__ e0, const float* __restrict__ e1,
    const float* __restrict__ e2) {
  const int bm0 = blockIdx.x * 256;
  const int bn0 = blockIdx.y * 256;
  if (MODE == 2 && bn0 > bm0 + 255) return;  // fully above causal diagonal
  const int z = blockIdx.z;
  const bf16* A = Aall + (long)z * sAz;
  const bf16* B = Ball + (long)z * sBz;

  __shared__ __align__(16) char smem[98304];
  const int tid = threadIdx.x;
  const int l = tid & 63, w = tid >> 6;
  const int wr = w >> 2, wc = w & 3;  // wave grid 2x4

  f32x4 acc[8][4] = {};

  const int nt = (MODE == 3) ? ((bm0 + 256) >> 5) : (K >> 5);

  // pre-swizzled global source granule for staging (see header comment)
  const int sg = (((l & 3) ^ ((l >> 3) & 3)) << 3);  // element offset, 8 bf16

  auto stageA = [&](int tt, int half) {
    char* dst = smem + (tt % 3) * 16384 + (half << 13) + (w << 10);
    int row = (half << 7) + (w << 4) + (l >> 2);
    gload_lds16(A + (long)(bm0 + row) * lda + (tt << 5) + sg, dst);
  };
  auto stageB = [&](int tt, int half) {
    char* dst = smem + 49152 + (tt % 3) * 16384 + (half << 13) + (w << 10);
    int row = (half << 7) + (w << 4) + (l >> 2);
    gload_lds16(B + (long)(bn0 + row) * ldb + (tt << 5) + sg, dst);
  };

  // swizzled frag-read slot and per-wave byte bases (loop-invariant)
  const int rslot = (((l >> 4) ^ ((l >> 1) & 3)) << 4);
  const int abyte = (((wr << 7) + (l & 15)) << 6) + rslot;
  const int bbyte = (((wc << 6) + (l & 15)) << 6) + rslot;

  // prologue: stage tiles 0 and 1 fully (regions 0, 1)
  stageA(0, 0); stageA(0, 1); stageB(0, 0); stageB(0, 1);
  if (nt > 1) { stageA(1, 0); stageA(1, 1); stageB(1, 0); stageB(1, 1); }
  if (nt > 1) asm volatile("s_waitcnt vmcnt(4)" ::: "memory");  // drain tile 0
  else        asm volatile("s_waitcnt vmcnt(0)" ::: "memory");
  __builtin_amdgcn_sched_barrier(0);
  asm volatile("s_barrier" ::: "memory");

  short8 a0, a1, a2, a3, a4, a5, a6, a7;
  short8 be0, be1, be2, be3, bo0, bo1, bo2, bo3;

  // pre-read tile 0's first-phase frags (region 0)
  {
    const char* Ab_ = smem;
    const char* Bb_ = smem + 49152;
    a0 = *(const short8*)(Ab_ + abyte + 0 * 1024);
    a1 = *(const short8*)(Ab_ + abyte + 1 * 1024);
    a2 = *(const short8*)(Ab_ + abyte + 2 * 1024);
    a3 = *(const short8*)(Ab_ + abyte + 3 * 1024);
    be0 = *(const short8*)(Bb_ + bbyte + 0 * 1024);
    be1 = *(const short8*)(Bb_ + bbyte + 1 * 1024);
    be2 = *(const short8*)(Bb_ + bbyte + 2 * 1024);
    be3 = *(const short8*)(Bb_ + bbyte + 3 * 1024);
  }
  asm volatile("s_waitcnt lgkmcnt(0)" ::: "memory");
  __builtin_amdgcn_sched_barrier(0);

#define MROW(R, AF, B0, B1, B2, B3)                                           \
  acc[R][0] = __builtin_amdgcn_mfma_f32_16x16x32_bf16(AF, B0, acc[R][0], 0, 0, 0); \
  acc[R][1] = __builtin_amdgcn_mfma_f32_16x16x32_bf16(AF, B1, acc[R][1], 0, 0, 0); \
  acc[R][2] = __builtin_amdgcn_mfma_f32_16x16x32_bf16(AF, B2, acc[R][2], 0, 0, 0); \
  acc[R][3] = __builtin_amdgcn_mfma_f32_16x16x32_bf16(AF, B3, acc[R][3], 0, 0, 0);

#define TILE(T, bc0, bc1, bc2, bc3, bn0_, bn1_, bn2_, bn3_)                   \
  {                                                                           \
    const int t_ = (T);                                                       \
    const char* Ab_ = smem + (t_ % 3) * 16384;                                \
    /* phase 0: read a4..7(t) | stage(t+2,h0) | MFMA a0..3 x Bcur */          \
    a4 = *(const short8*)(Ab_ + abyte + 4 * 1024);                            \
    a5 = *(const short8*)(Ab_ + abyte + 5 * 1024);                            \
    a6 = *(const short8*)(Ab_ + abyte + 6 * 1024);                            \
    a7 = *(const short8*)(Ab_ + abyte + 7 * 1024);                            \
    if (t_ + 2 < nt) { stageA(t_ + 2, 0); stageB(t_ + 2, 0); }                \
    __builtin_amdgcn_sched_barrier(0);                                        \
    __builtin_amdgcn_s_setprio(1);                                            \
    MROW(0, a0, bc0, bc1, bc2, bc3)                                           \
    MROW(1, a1, bc0, bc1, bc2, bc3)                                           \
    MROW(2, a2, bc0, bc1, bc2, bc3)                                           \
    MROW(3, a3, bc0, bc1, bc2, bc3)                                           \
    __builtin_amdgcn_s_setprio(0);                                            \
    __builtin_amdgcn_sched_barrier(0);                                        \
    asm volatile("s_waitcnt lgkmcnt(0)" ::: "memory");                        \
    if (t_ + 2 < nt) asm volatile("s_waitcnt vmcnt(2)" ::: "memory");         \
    else             asm volatile("s_waitcnt vmcnt(0)" ::: "memory");         \
    __builtin_amdgcn_sched_barrier(0);                                        \
    asm volatile("s_barrier" ::: "memory");                                   \
    /* phase 1: read tile t+1 frags | stage(t+2,h1) | MFMA a4..7 x Bcur */    \
    if (t_ + 1 < nt) {                                                        \
      const char* An_ = smem + ((t_ + 1) % 3) * 16384;                        \
      const char* Bn_ = smem + 49152 + ((t_ + 1) % 3) * 16384;                \
      a0 = *(const short8*)(An_ + abyte + 0 * 1024);                          \
      a1 = *(const short8*)(An_ + abyte + 1 * 1024);                          \
      a2 = *(const short8*)(An_ + abyte + 2 * 1024);                          \
      a3 = *(const short8*)(An_ + abyte + 3 * 1024);                          \
      bn0_ = *(const short8*)(Bn_ + bbyte + 0 * 1024);                        \
      bn1_ = *(const short8*)(Bn_ + bbyte + 1 * 1024);                        \
      bn2_ = *(const short8*)(Bn_ + bbyte + 2 * 1024);                        \
      bn3_ = *(const short8*)(Bn_ + bbyte + 3 * 1024);                        \
    }                                                                         \
    if (t_ + 2 < nt) { stageA(t_ + 2, 1); stageB(t_ + 2, 1); }                \
    __builtin_amdgcn_sched_barrier(0);                                        \
    __builtin_amdgcn_s_setprio(1);                                            \
    MROW(4, a4, bc0, bc1, bc2, bc3)                                           \
    MROW(5, a5, bc0, bc1, bc2, bc3)                                           \
    MROW(6, a6, bc0, bc1, bc2, bc3)                                           \
    MROW(7, a7, bc0, bc1, bc2, bc3)                                           \
    __builtin_amdgcn_s_setprio(0);                                            \
    __builtin_amdgcn_sched_barrier(0);                                        \
    asm volatile("s_waitcnt lgkmcnt(0)" ::: "memory");                        \
    __builtin_amdgcn_sched_barrier(0);                                        \
    asm volatile("s_barrier" ::: "memory");                                   \
  }

  for (int t = 0; t < nt; t += 2) {
    TILE(t,     be0, be1, be2, be3, bo0, bo1, bo2, bo3);
    TILE(t + 1, bo0, bo1, bo2, bo3, be0, be1, be2, be3);
  }
#undef TILE
#undef MROW

  // epilogue: C/D mapping col = lane&15, row = (lane>>4)*4 + reg
  const int lc = l & 15, lr4 = (l >> 4) << 2;
#pragma unroll
  for (int fr = 0; fr < 8; ++fr) {
    int gr0 = bm0 + (wr << 7) + fr * 16 + lr4;
#pragma unroll
    for (int fc = 0; fc < 4; ++fc) {
      int gc = bn0 + (wc << 6) + fc * 16 + lc;
#pragma unroll
      for (int qv = 0; qv < 4; ++qv) {
        int gr = gr0 + qv;
        float a = acc[fr][fc][qv];
        if (MODE == 0) {
          ((float*)Call + (long)z * sCz)[(long)gr * N + gc] = a;
        } else if (MODE == 1) {
          float val = a + e0[z * Dh + gc];
          float sil = val / (1.f + __expf(-val));
          int bb = gr >> 11;
          float g = e1[(z * Bh + bb) * Dh + gc];
          ((bf16*)Call + (long)z * sCz)[(long)gr * N + gc] =
              __float2bfloat16(sil * g);
        } else if (MODE == 2) {
          ((float*)Call + (long)z * sCz)[(long)gr * N + gc] = a * INV_SQRT_D;
        } else if (MODE == 3) {
          ((bf16*)Call + (long)z * sCz)[(long)gr * N + gc] = __float2bfloat16(a);
        } else {
          float val = a + e0[gc];
          float sil = val / (1.f + __expf(-val));
          int bb = gr >> 11;
          ((float*)Call)[(long)gr * N + gc] =
              e2[(long)gr * N + gc] + e1[bb * Dh + gc] * sil;
        }
      }
    }
  }
}

// f32 -> bf16 elementwise for 3 tensors of DD4 elements each (y selects)
__global__ __launch_bounds__(256) void cvt3_kernel(
    const float* __restrict__ s0, const float* __restrict__ s1,
    const float* __restrict__ s2, bf16* __restrict__ o0, bf16* __restrict__ o1,
    bf16* __restrict__ o2, long n) {
  const float* in = (blockIdx.y == 0) ? s0 : (blockIdx.y == 1) ? s1 : s2;
  bf16* out = (blockIdx.y == 0) ? o0 : (blockIdx.y == 1) ? o1 : o2;
  long i = ((long)blockIdx.x * 256 + threadIdx.x) * 4;
  if (i >= n) return;
  float4 v = *(const float4*)(in + i);
  out[i + 0] = __float2bfloat16(v.x);
  out[i + 1] = __float2bfloat16(v.y);
  out[i + 2] = __float2bfloat16(v.z);
  out[i + 3] = __float2bfloat16(v.w);
}

// bf16 transpose [4][S][D] -> [4][D][S], 64x64 tiles
__global__ __launch_bounds__(256) void transpose_kernel(const bf16* __restrict__ in,
                                                        bf16* __restrict__ out) {
  __shared__ bf16 t[64][65];
  int b = blockIdx.z;
  int s0 = blockIdx.x * 64, d0 = blockIdx.y * 64;
  const bf16* ib = in + (long)b * Sh * Dh;
  bf16* ob = out + (long)b * Sh * Dh;
  int tx = threadIdx.x & 63, ty = threadIdx.x >> 6;
#pragma unroll
  for (int r = ty; r < 64; r += 4) t[r][tx] = ib[(long)(s0 + r) * Dh + d0 + tx];
  __syncthreads();
#pragma unroll
  for (int r = ty; r < 64; r += 4) ob[(long)(d0 + r) * Sh + s0 + tx] = t[tx][r];
}

// LN over D per (b,s) row of x -> bf16
__global__ __launch_bounds__(256) void ln1_kernel(const float* __restrict__ x,
    const float* __restrict__ g, const float* __restrict__ b, bf16* __restrict__ out) {
  __shared__ float sm4[4];
  long r = blockIdx.x;
  const float* row = x + r * Dh;
  float v[8];
  float s = 0.f, s2 = 0.f;
#pragma unroll
  for (int c = 0; c < 8; ++c) {
    float t = row[threadIdx.x + c * 256];
    v[c] = t; s += t; s2 += t * t;
  }
  s = block_sum(s, sm4);
  s2 = block_sum(s2, sm4);
  float mean = s * (1.f / Dh);
  float rstd = rsqrtf(s2 * (1.f / Dh) - mean * mean + LNEPS);
#pragma unroll
  for (int c = 0; c < 8; ++c) {
    int o = threadIdx.x + c * 256;
    out[r * Dh + o] = __float2bfloat16((v[c] - mean) * rstd * g[o] + b[o]);
  }
}

// outbd[b*D+d] += (1/S) * sum over an s-chunk of in[b,s,d]
__global__ __launch_bounds__(256) void meanrow_kernel(const bf16* __restrict__ in,
                                                      float* __restrict__ outbd) {
  int gid = blockIdx.x * 256 + threadIdx.x;
  int s0 = blockIdx.y * 128;
  long base = ((long)(gid >> 11) * Sh + s0) * Dh + (gid & 2047);
  float s = 0.f;
  for (int t = 0; t < 128; ++t) s += __bfloat162float(in[base + (long)t * Dh]);
  atomicAdd(&outbd[gid], s * (1.f / Sh));
}

// Per (n,i): LN prc row, add proto_w; n<3: dot with ctx -> routing; n==3: store ps3
__global__ __launch_bounds__(256) void route_kernel(
    const float* __restrict__ prc, const float* __restrict__ proto_w,
    const float* __restrict__ pln_g, const float* __restrict__ pln_b,
    const float* __restrict__ gate, const float* __restrict__ ctx,
    float* __restrict__ routing, float* __restrict__ ps3) {
  __shared__ float sm4[4];
  int i = blockIdx.x, n = blockIdx.y;
  long rb = ((long)n * Dh + i) * Dh;
  float v[8];
  float s = 0.f, s2 = 0.f;
#pragma unroll
  for (int c = 0; c < 8; ++c) {
    float t = prc[rb + threadIdx.x + c * 256];
    v[c] = t; s += t; s2 += t * t;
  }
  s = block_sum(s, sm4);
  s2 = block_sum(s2, sm4);
  float mean = s * (1.f / Dh);
  float rstd = rsqrtf(s2 * (1.f / Dh) - mean * mean + LNEPS);
  if (n == 3) {
#pragma unroll
    for (int c = 0; c < 8; ++c) {
      int o = threadIdx.x + c * 256;
      float ps = proto_w[rb + o] + (v[c] - mean) * rstd * pln_g[3 * Dh + o] + pln_b[3 * Dh + o];
      ps3[(long)i * Dh + o] = ps;
    }
  } else {
    float acc[4] = {0.f, 0.f, 0.f, 0.f};
#pragma unroll
    for (int c = 0; c < 8; ++c) {
      int o = threadIdx.x + c * 256;
      float ps = proto_w[rb + o] + (v[c] - mean) * rstd * pln_g[n * Dh + o] + pln_b[n * Dh + o];
#pragma unroll
      for (int b = 0; b < 4; ++b) acc[b] += ps * ctx[b * Dh + o];
    }
    for (int b = 0; b < 4; ++b) {
      float r = block_sum(acc[b], sm4);
      if (threadIdx.x == 0)
        routing[(n * 4 + b) * Dh + i] = r * INV_SQRT_D + gate[n * Dh + i];
    }
  }
}

__global__ __launch_bounds__(256) void route_o_kernel(
    const float* __restrict__ ps3, const float* __restrict__ ctxo,
    const float* __restrict__ gate, float* __restrict__ routing) {
  __shared__ float sm4[4];
  int i = blockIdx.x;
  float acc[4] = {0.f, 0.f, 0.f, 0.f};
#pragma unroll
  for (int c = 0; c < 8; ++c) {
    int o = threadIdx.x + c * 256;
    float p = ps3[(long)i * Dh + o];
#pragma unroll
    for (int b = 0; b < 4; ++b) acc[b] += p * ctxo[b * Dh + o];
  }
  for (int b = 0; b < 4; ++b) {
    float r = block_sum(acc[b], sm4);
    if (threadIdx.x == 0)
      routing[(12 + b) * Dh + i] = r * INV_SQRT_D + gate[3 * Dh + i];
  }
}

__global__ __launch_bounds__(256) void masnorm_kernel(const float* __restrict__ rin,
                                                      float* __restrict__ gout) {
  __shared__ float sm4[4];
  long r = blockIdx.x;
  float m = 0.f;
#pragma unroll
  for (int c = 0; c < 8; ++c)
    m = fmaxf(m, fabsf(rin[r * Dh + threadIdx.x + c * 256]));
  m = block_max(m, sm4);
  float inv = 1.f / (m + 1e-9f);
#pragma unroll
  for (int c = 0; c < 8; ++c) {
    int o = threadIdx.x + c * 256;
    gout[r * Dh + o] = rin[r * Dh + o] * inv;
  }
}

__global__ __launch_bounds__(256) void rope_table_kernel(float* __restrict__ cosT,
                                                         float* __restrict__ sinT) {
  int idx = blockIdx.x * 256 + threadIdx.x;
  int t = idx >> 10, f = idx & 1023;
  float inv_freq = expf(-(float)f * (9.210340371976184f / 1024.f));
  float ang = (float)t * inv_freq;
  cosT[idx] = cosf(ang);
  sinT[idx] = sinf(ang);
}

__global__ __launch_bounds__(256) void rope_kernel(bf16* __restrict__ q, bf16* __restrict__ k,
    const int* __restrict__ pos, const float* __restrict__ cosT,
    const float* __restrict__ sinT) {
  long r = blockIdx.x;
  int s = (int)(r & (Sh - 1));
  int p = pos[s];
#pragma unroll
  for (int c = 0; c < 4; ++c) {
    int t = threadIdx.x + c * 256;
    float cv = cosT[(long)p * HALF + t];
    float sv = sinT[(long)p * HALF + t];
    long i1 = r * Dh + t, i2 = i1 + HALF;
    float q1 = __bfloat162float(q[i1]), q2 = __bfloat162float(q[i2]);
    q[i1] = __float2bfloat16(q1 * cv - q2 * sv);
    q[i2] = __float2bfloat16(q2 * cv + q1 * sv);
    float k1 = __bfloat162float(k[i1]), k2 = __bfloat162float(k[i2]);
    k[i1] = __float2bfloat16(k1 * cv - k2 * sv);
    k[i2] = __float2bfloat16(k2 * cv + k1 * sv);
  }
}

// causal row softmax: read f32 scores (k<=q), write bf16 probs, zero-fill row
__global__ __launch_bounds__(256) void softmax_kernel(const float* __restrict__ scores,
                                                      bf16* __restrict__ probs) {
  __shared__ float buf[Sh];
  __shared__ float sm4[4];
  long r = blockIdx.x;
  int qi = (int)(r & (Sh - 1));
  const float* row = scores + r * (long)Sh;
  bf16* prow = probs + r * (long)Sh;
  int n = qi + 1;
  float m = -3.0e38f;
  for (int o = threadIdx.x; o < n; o += 256) {
    float x = row[o]; buf[o] = x; m = fmaxf(m, x);
  }
  m = block_max(m, sm4);
  float s = 0.f;
  for (int o = threadIdx.x; o < n; o += 256) {
    float e = __expf(buf[o] - m); buf[o] = e; s += e;
  }
  s = block_sum(s, sm4);
  float inv = 1.f / s;
  for (int o = threadIdx.x; o < n; o += 256) prow[o] = __float2bfloat16(buf[o] * inv);
  for (int o = n + (int)threadIdx.x; o < Sh; o += 256) prow[o] = __float2bfloat16(0.f);
}

extern "C" void kernel_launch(void* const* d_in, const int* in_sizes, int n_in,
                              void* d_out, int out_size, void* d_ws, size_t ws_size,
                              hipStream_t stream) {
  const float* x       = (const float*)d_in[0];
  const int*   pos     = (const int*)d_in[1];
  const float* ln1_g   = (const float*)d_in[2];
  const float* ln1_b   = (const float*)d_in[3];
  const float* mu_w    = (const float*)d_in[4];
  const float* mu_b    = (const float*)d_in[5];
  const float* proto_w = (const float*)d_in[6];
  const float* gate    = (const float*)d_in[7];
  const float* pt_w    = (const float*)d_in[8];
  const float* pln_g   = (const float*)d_in[9];
  const float* pln_b   = (const float*)d_in[10];
  const float* incoming= (const float*)d_in[11];

  // workspace layout (~302 MB); scores f32 lives in d_out (dead until o-proj)
  char* w = (char*)d_ws;
  const long BF = 33554432L;  // bytes of one bf16 [8192][2048]
  bf16*  ln1    = (bf16*)(w);
  bf16*  qb     = (bf16*)(w + BF);
  bf16*  kb     = (bf16*)(w + 2 * BF);
  bf16*  vb     = (bf16*)(w + 3 * BF);
  bf16*  attn   = (bf16*)(w + 4 * BF);
  bf16*  mu_wb  = (bf16*)(w + 5 * BF);         // [4][D][D] bf16
  bf16*  ptw_b  = (bf16*)(w + 6 * BF);         // aliased: later vT [4][D][S]
  bf16*  vT     = ptw_b;
  bf16*  inc_b  = (bf16*)(w + 7 * BF);         // aliased: later probs [4][S][S]
  bf16*  probs  = inc_b;
  float* ps3    = (float*)(w + 8 * BF);                 // [2048][2048] f32
  float* cosT   = (float*)(w + 8 * BF + 16777216L);
  float* sinT   = cosT + (long)Sh * HALF;
  float* ctx    = sinT + (long)Sh * HALF;               // [4][2048]
  float* ctxo   = ctx + Bh * Dh;
  float* routing= ctxo + Bh * Dh;                       // [16][2048]
  float* gating = routing + 16 * Dh;                    // [16][2048]
  float* scores = (float*)d_out;                        // f32 [4][2048][2048]

  const long DD4 = 4L * Dh * Dh;

  hipMemsetAsync(ctx, 0, 2L * Bh * Dh * sizeof(float), stream);

  rope_table_kernel<<<(Sh * HALF) / 256, 256, 0, stream>>>(cosT, sinT);
  cvt3_kernel<<<dim3(DD4 / 1024, 3), 256, 0, stream>>>(
      mu_w, incoming, pt_w, mu_wb, inc_b, ptw_b, DD4);
  ln1_kernel<<<NROW, 256, 0, stream>>>(x, ln1_g, ln1_b, ln1);
  meanrow_kernel<<<dim3(32, 16), 256, 0, stream>>>(ln1, ctx);
  // prc[n] = incoming[n] @ pt_w[n]^T  -> scores (f32, in d_out)
  pgemm<0><<<dim3(8, 8, 4), 512, 0, stream>>>(
      inc_b, ptw_b, scores, Dh, Dh, Dh, Dh,
      (long)Dh * Dh, (long)Dh * Dh, (long)Dh * Dh, nullptr, nullptr, nullptr);
  route_kernel<<<dim3(Dh, 4), 256, 0, stream>>>(scores, proto_w, pln_g, pln_b,
                                                gate, ctx, routing, ps3);
  masnorm_kernel<<<12, 256, 0, stream>>>(routing, gating);
  // q/k/v = gating * silu(ln1 @ mu_w[n]^T + mu_b[n])
  pgemm<1><<<dim3(32, 8, 3), 512, 0, stream>>>(
      ln1, mu_wb, qb, Dh, Dh, Dh, Dh,
      0L, (long)Dh * Dh, (long)NROW * Dh, mu_b, gating, nullptr);
  rope_kernel<<<NROW, 256, 0, stream>>>(qb, kb, pos, cosT, sinT);
  // scores = q @ k^T * inv_sqrt_d (causal blocks only)
  pgemm<2><<<dim3(8, 8, 4), 512, 0, stream>>>(
      qb, kb, scores, Sh, Dh, Dh, Dh,
      (long)Sh * Dh, (long)Sh * Dh, (long)Sh * Sh, nullptr, nullptr, nullptr);
  softmax_kernel<<<Bh * Sh, 256, 0, stream>>>(scores, probs);
  transpose_kernel<<<dim3(32, 32, 4), 256, 0, stream>>>(vb, vT);
  // attn = probs @ v = probs @ vT^T   (K bounded causally per row tile)
  pgemm<3><<<dim3(8, 8, 4), 512, 0, stream>>>(
      probs, vT, attn, Dh, Sh, Sh, Sh,
      (long)Sh * Sh, (long)Dh * Sh, (long)Sh * Dh, nullptr, nullptr, nullptr);
  meanrow_kernel<<<dim3(32, 16), 256, 0, stream>>>(attn, ctxo);
  route_o_kernel<<<Dh, 256, 0, stream>>>(ps3, ctxo, gate, routing);
  masnorm_kernel<<<4, 256, 0, stream>>>(routing + 12 * Dh, gating + 12 * Dh);
  // out = x + gating_o * silu(attn @ mu_w[3]^T + mu_b[3])
  pgemm<4><<<dim3(32, 8, 1), 512, 0, stream>>>(
      attn, mu_wb + 3L * Dh * Dh, d_out, Dh, Dh, Dh, Dh,
      0L, 0L, 0L, mu_b + 3 * Dh, gating + 12 * Dh, x);
}

// Round 8
// 678.244 us; speedup vs baseline: 1.0654x; 1.0654x over previous
//
#include <hip/hip_runtime.h>
#include <hip/hip_bf16.h>

#define Dh 2048
#define Bh 4
#define Sh 2048
#define NROW 8192          // B*S
#define HALF 1024
#define INV_SQRT_D 0.022097086912079608f
#define LNEPS 1e-5f

typedef __hip_bfloat16 bf16;
typedef short short8 __attribute__((ext_vector_type(8)));
typedef float f32x4 __attribute__((ext_vector_type(4)));

__device__ inline float warp_sum(float x) {
#pragma unroll
  for (int o = 32; o > 0; o >>= 1) x += __shfl_down(x, o);
  return x;
}
__device__ inline float warp_max(float x) {
#pragma unroll
  for (int o = 32; o > 0; o >>= 1) x = fmaxf(x, __shfl_down(x, o));
  return x;
}
__device__ inline float block_sum(float x, float* sm4) {
  x = warp_sum(x);
  int w = threadIdx.x >> 6;
  if ((threadIdx.x & 63) == 0) sm4[w] = x;
  __syncthreads();
  float r = sm4[0] + sm4[1] + sm4[2] + sm4[3];
  __syncthreads();
  return r;
}
__device__ inline float block_max(float x, float* sm4) {
  x = warp_max(x);
  int w = threadIdx.x >> 6;
  if ((threadIdx.x & 63) == 0) sm4[w] = x;
  __syncthreads();
  float r = fmaxf(fmaxf(sm4[0], sm4[1]), fmaxf(sm4[2], sm4[3]));
  __syncthreads();
  return r;
}

// async global->LDS, 16B per lane; LDS dest is wave-uniform base + lane*16
__device__ inline void gload_lds16(const void* g, void* lds) {
  __builtin_amdgcn_global_load_lds(
      (const __attribute__((address_space(1))) unsigned int*)(unsigned long long)g,
      (__attribute__((address_space(3))) unsigned int*)(unsigned long long)lds,
      16, 0, 0);
}

#define MM(R, AF)                                                              \
  acc[R][0] = __builtin_amdgcn_mfma_f32_16x16x32_bf16(AF, b0, acc[R][0], 0, 0, 0); \
  acc[R][1] = __builtin_amdgcn_mfma_f32_16x16x32_bf16(AF, b1, acc[R][1], 0, 0, 0); \
  acc[R][2] = __builtin_amdgcn_mfma_f32_16x16x32_bf16(AF, b2, acc[R][2], 0, 0, 0); \
  acc[R][3] = __builtin_amdgcn_mfma_f32_16x16x32_bf16(AF, b3, acc[R][3], 0, 0, 0);

// ---------------------------------------------------------------------------
// MFMA bf16 GEMM: C[M,N] = A[M,K] @ B[N,K]^T. 256x256 tile, BK=32, 8 waves
// (2Mx4N), per-wave 128x64. LDS 64KB: 2 buf x (A 16KB + B 16KB).
// R8: R4's validated skeleton (best measured: 219us) with ALL setprio /
// mid-loop sched_barrier fences REMOVED (T5 is null-to-negative on
// non-role-split GEMM per m190; fences pin the compiler's fine-grained
// lgkmcnt pipelining). Only sync kept: mid barrier (WAR: stageB(t+2) writes
// the B region read at tile top), end vmcnt(2)+barrier (RAW: gates tile
// t+1's stages), and lgkmcnt(0) drains before each barrier (read-return
// published before DMA overwrite). Stage addresses hoisted to base+tt*64B.
// T2 swizzle (validated, 0 conflicts): stage pre-swizzles GLOBAL source
// granule G=(l&3)^((l>>3)&3); frag reads use slot (l>>4)^((l>>1)&3).
// vmcnt ledger (steady): entry <=2 [B(t+1)]; +stageA(t+1) 2; +stageB(t+2) 2
// = 6; end needs B(t+1),A(t+1) done -> drain 4 oldest -> vmcnt(2).
// MODE 0: C f32 = acc                                        (prc)
// MODE 1: C bf16 = silu(acc + e0[z*D+c]) * e1[(z*4+b)*D+c]   (qkv)
// MODE 2: C f32 = acc * INV_SQRT_D, skip blocks above diagonal (QK^T)
// MODE 4: C f32 = e2[r*N+c] + e1[b*D+c] * silu(acc + e0[c])  (o-proj+resid)
// ---------------------------------------------------------------------------
template <int MODE>
__global__ __launch_bounds__(512) void pgemm(
    const bf16* __restrict__ Aall, const bf16* __restrict__ Ball,
    void* __restrict__ Call, int N, int K, int lda, int ldb,
    long sAz, long sBz, long sCz,
    const float* __restrict__ e0, const float* __restrict__ e1,
    const float* __restrict__ e2) {
  const int bm0 = blockIdx.x * 256;
  const int bn0 = blockIdx.y * 256;
  if (MODE == 2 && bn0 > bm0 + 255) return;  // fully above causal diagonal
  const int z = blockIdx.z;
  const bf16* A = Aall + (long)z * sAz;
  const bf16* B = Ball + (long)z * sBz;

  __shared__ __align__(16) char smem[65536];
  const int tid = threadIdx.x;
  const int l = tid & 63, w = tid >> 6;
  const int wr = w >> 2, wc = w & 3;  // wave grid 2x4

  f32x4 acc[8][4] = {};
  const int nt = K >> 5;

  // staging bases (hoisted; per tile just + tt*64 bytes)
  const int sg = (((l & 3) ^ ((l >> 3) & 3)) << 3);  // pre-swizzled granule
  const int srow = (w << 4) + (l >> 2);              // row within 128-half
  const bf16* aS0 = A + (long)(bm0 + srow) * lda + sg;
  const bf16* aS1 = A + (long)(bm0 + 128 + srow) * lda + sg;
  const bf16* bS0 = B + (long)(bn0 + srow) * ldb + sg;
  const bf16* bS1 = B + (long)(bn0 + 128 + srow) * ldb + sg;
  char* const dA = smem + (w << 10);
  char* const dB = smem + 16384 + (w << 10);

  auto stageA = [&](int tt) {
    int boff = (tt & 1) << 15;
    gload_lds16(aS0 + (tt << 5), dA + boff);
    gload_lds16(aS1 + (tt << 5), dA + boff + 8192);
  };
  auto stageB = [&](int tt) {
    int boff = (tt & 1) << 15;
    gload_lds16(bS0 + (tt << 5), dB + boff);
    gload_lds16(bS1 + (tt << 5), dB + boff + 8192);
  };

  // prologue: tile0 fully + tile1's B (steady-state pattern)
  stageA(0); stageB(0);
  if (nt > 1) stageB(1);
  if (nt > 1) asm volatile("s_waitcnt vmcnt(2)" ::: "memory");
  else        asm volatile("s_waitcnt vmcnt(0)" ::: "memory");
  __builtin_amdgcn_sched_barrier(0);
  asm volatile("s_barrier" ::: "memory");

  const int rslot = (((l >> 4) ^ ((l >> 1) & 3)) << 4);
  const int abyte = (((wr << 7) + (l & 15)) << 6) + rslot;
  const int bbyte = (((wc << 6) + (l & 15)) << 6) + rslot;

  for (int t = 0; t < nt; ++t) {
    const char* Ab = smem + ((t & 1) << 15);
    const char* Bb = Ab + 16384;
    short8 b0 = *(const short8*)(Bb + bbyte);
    short8 b1 = *(const short8*)(Bb + bbyte + 1024);
    short8 b2 = *(const short8*)(Bb + bbyte + 2048);
    short8 b3 = *(const short8*)(Bb + bbyte + 3072);
    short8 a0 = *(const short8*)(Ab + abyte);
    short8 a1 = *(const short8*)(Ab + abyte + 1024);
    short8 a2 = *(const short8*)(Ab + abyte + 2048);
    short8 a3 = *(const short8*)(Ab + abyte + 3072);
    if (t + 1 < nt) stageA(t + 1);
    MM(0, a0) MM(1, a1) MM(2, a2) MM(3, a3)
    asm volatile("s_waitcnt lgkmcnt(0)" ::: "memory");
    asm volatile("s_barrier" ::: "memory");  // mid: B region read-published
    short8 a4 = *(const short8*)(Ab + abyte + 4096);
    short8 a5 = *(const short8*)(Ab + abyte + 5120);
    short8 a6 = *(const short8*)(Ab + abyte + 6144);
    short8 a7 = *(const short8*)(Ab + abyte + 7168);
    if (t + 2 < nt) stageB(t + 2);
    MM(4, a4) MM(5, a5) MM(6, a6) MM(7, a7)
    if (t < nt - 1) {
      asm volatile("s_waitcnt lgkmcnt(0)" ::: "memory");
      if (t + 2 < nt) asm volatile("s_waitcnt vmcnt(2)" ::: "memory");
      else            asm volatile("s_waitcnt vmcnt(0)" ::: "memory");
      __builtin_amdgcn_sched_barrier(0);
      asm volatile("s_barrier" ::: "memory");
    }
  }

  // epilogue: C/D mapping col = lane&15, row = (lane>>4)*4 + reg
  const int lc = l & 15, lr4 = (l >> 4) << 2;
#pragma unroll
  for (int fr = 0; fr < 8; ++fr) {
    int gr0 = bm0 + (wr << 7) + fr * 16 + lr4;
#pragma unroll
    for (int fc = 0; fc < 4; ++fc) {
      int gc = bn0 + (wc << 6) + fc * 16 + lc;
#pragma unroll
      for (int qv = 0; qv < 4; ++qv) {
        int gr = gr0 + qv;
        float a = acc[fr][fc][qv];
        if (MODE == 0) {
          ((float*)Call + (long)z * sCz)[(long)gr * N + gc] = a;
        } else if (MODE == 1) {
          float val = a + e0[z * Dh + gc];
          float sil = val / (1.f + __expf(-val));
          int bb = gr >> 11;
          float g = e1[(z * Bh + bb) * Dh + gc];
          ((bf16*)Call + (long)z * sCz)[(long)gr * N + gc] =
              __float2bfloat16(sil * g);
        } else if (MODE == 2) {
          ((float*)Call + (long)z * sCz)[(long)gr * N + gc] = a * INV_SQRT_D;
        } else {
          float val = a + e0[gc];
          float sil = val / (1.f + __expf(-val));
          int bb = gr >> 11;
          ((float*)Call)[(long)gr * N + gc] =
              e2[(long)gr * N + gc] + e1[bb * Dh + gc] * sil;
        }
      }
    }
  }
}

// ---------------------------------------------------------------------------
// Balanced causal PV GEMM: attn = probs @ vT^T. BM=128, BN=256, BK=32,
// 8 waves 2x4, per-wave 64x64 (acc 64 VGPR -> multi-block occupancy).
// LDS 48KB: 2 buf x (A 8KB + B 16KB). Same sync skeleton as pgemm.
// nt = (bm0+128)/32 varies 4..64 per m-tile: 512 blocks with complementary
// remap (blocks fid and fid+256 get mi and 15-mi) so CU pair-load is a
// uniform ~68 tiles. vmcnt ledger: entry <=2 [B(t+1)]; +A(t+1) 1; +B(t+2) 2
// = 5; drain 3 oldest -> vmcnt(2). Prologue A0(1),B0(2),B1(2)=5 -> vmcnt(2).
// ---------------------------------------------------------------------------
__global__ __launch_bounds__(512) void pgemm_h(
    const bf16* __restrict__ Aall, const bf16* __restrict__ Ball,
    bf16* __restrict__ Call, int N, int lda, int ldb,
    long sAz, long sBz, long sCz) {
  const int fid = blockIdx.x;
  const int p = fid >> 8, q = fid & 255;
  const int mh = q >> 5;
  const int z = (q >> 3) & 3, ni = q & 7;
  const int mi = p ? (15 - mh) : mh;
  const int bm0 = mi * 128, bn0 = ni * 256;
  const bf16* A = Aall + (long)z * sAz;
  const bf16* B = Ball + (long)z * sBz;

  __shared__ __align__(16) char smem[49152];
  const int tid = threadIdx.x;
  const int l = tid & 63, w = tid >> 6;
  const int wr = w >> 2, wc = w & 3;
  f32x4 acc[4][4] = {};
  const int nt = (bm0 + 128) >> 5;

  const int sg = (((l & 3) ^ ((l >> 3) & 3)) << 3);
  const int srow = (w << 4) + (l >> 2);
  const bf16* aS = A + (long)(bm0 + srow) * lda + sg;
  const bf16* bS0 = B + (long)(bn0 + srow) * ldb + sg;
  const bf16* bS1 = B + (long)(bn0 + 128 + srow) * ldb + sg;
  char* const dA = smem + (w << 10);
  char* const dB = smem + 8192 + (w << 10);

  auto stageA = [&](int tt) {
    gload_lds16(aS + (tt << 5), dA + (tt & 1) * 24576);
  };
  auto stageB = [&](int tt) {
    int boff = (tt & 1) * 24576;
    gload_lds16(bS0 + (tt << 5), dB + boff);
    gload_lds16(bS1 + (tt << 5), dB + boff + 8192);
  };

  stageA(0); stageB(0);
  if (nt > 1) stageB(1);
  if (nt > 1) asm volatile("s_waitcnt vmcnt(2)" ::: "memory");
  else        asm volatile("s_waitcnt vmcnt(0)" ::: "memory");
  __builtin_amdgcn_sched_barrier(0);
  asm volatile("s_barrier" ::: "memory");

  const int rslot = (((l >> 4) ^ ((l >> 1) & 3)) << 4);
  const int abyte = (((wr << 6) + (l & 15)) << 6) + rslot;
  const int bbyte = (((wc << 6) + (l & 15)) << 6) + rslot;

  for (int t = 0; t < nt; ++t) {
    const char* Ab = smem + (t & 1) * 24576;
    const char* Bb = Ab + 8192;
    short8 b0 = *(const short8*)(Bb + bbyte);
    short8 b1 = *(const short8*)(Bb + bbyte + 1024);
    short8 b2 = *(const short8*)(Bb + bbyte + 2048);
    short8 b3 = *(const short8*)(Bb + bbyte + 3072);
    short8 a0 = *(const short8*)(Ab + abyte);
    short8 a1 = *(const short8*)(Ab + abyte + 1024);
    if (t + 1 < nt) stageA(t + 1);
    MM(0, a0) MM(1, a1)
    asm volatile("s_waitcnt lgkmcnt(0)" ::: "memory");
    asm volatile("s_barrier" ::: "memory");
    short8 a2 = *(const short8*)(Ab + abyte + 2048);
    short8 a3 = *(const short8*)(Ab + abyte + 3072);
    if (t + 2 < nt) stageB(t + 2);
    MM(2, a2) MM(3, a3)
    if (t < nt - 1) {
      asm volatile("s_waitcnt lgkmcnt(0)" ::: "memory");
      if (t + 2 < nt) asm volatile("s_waitcnt vmcnt(2)" ::: "memory");
      else            asm volatile("s_waitcnt vmcnt(0)" ::: "memory");
      __builtin_amdgcn_sched_barrier(0);
      asm volatile("s_barrier" ::: "memory");
    }
  }

  const int lc = l & 15, lr4 = (l >> 4) << 2;
  bf16* C = Call + (long)z * sCz;
#pragma unroll
  for (int fr = 0; fr < 4; ++fr) {
    int gr0 = bm0 + (wr << 6) + fr * 16 + lr4;
#pragma unroll
    for (int fc = 0; fc < 4; ++fc) {
      int gc = bn0 + (wc << 6) + fc * 16 + lc;
#pragma unroll
      for (int qv = 0; qv < 4; ++qv) {
        C[(long)(gr0 + qv) * N + gc] = __float2bfloat16(acc[fr][fc][qv]);
      }
    }
  }
}

// f32 -> bf16 elementwise for 3 tensors of DD4 elements each (y selects)
__global__ __launch_bounds__(256) void cvt3_kernel(
    const float* __restrict__ s0, const float* __restrict__ s1,
    const float* __restrict__ s2, bf16* __restrict__ o0, bf16* __restrict__ o1,
    bf16* __restrict__ o2, long n) {
  const float* in = (blockIdx.y == 0) ? s0 : (blockIdx.y == 1) ? s1 : s2;
  bf16* out = (blockIdx.y == 0) ? o0 : (blockIdx.y == 1) ? o1 : o2;
  long i = ((long)blockIdx.x * 256 + threadIdx.x) * 4;
  if (i >= n) return;
  float4 v = *(const float4*)(in + i);
  out[i + 0] = __float2bfloat16(v.x);
  out[i + 1] = __float2bfloat16(v.y);
  out[i + 2] = __float2bfloat16(v.z);
  out[i + 3] = __float2bfloat16(v.w);
}

// bf16 transpose [4][S][D] -> [4][D][S], 64x64 tiles
__global__ __launch_bounds__(256) void transpose_kernel(const bf16* __restrict__ in,
                                                        bf16* __restrict__ out) {
  __shared__ bf16 t[64][65];
  int b = blockIdx.z;
  int s0 = blockIdx.x * 64, d0 = blockIdx.y * 64;
  const bf16* ib = in + (long)b * Sh * Dh;
  bf16* ob = out + (long)b * Sh * Dh;
  int tx = threadIdx.x & 63, ty = threadIdx.x >> 6;
#pragma unroll
  for (int r = ty; r < 64; r += 4) t[r][tx] = ib[(long)(s0 + r) * Dh + d0 + tx];
  __syncthreads();
#pragma unroll
  for (int r = ty; r < 64; r += 4) ob[(long)(d0 + r) * Sh + s0 + tx] = t[tx][r];
}

// LN over D per (b,s) row of x -> bf16
__global__ __launch_bounds__(256) void ln1_kernel(const float* __restrict__ x,
    const float* __restrict__ g, const float* __restrict__ b, bf16* __restrict__ out) {
  __shared__ float sm4[4];
  long r = blockIdx.x;
  const float* row = x + r * Dh;
  float v[8];
  float s = 0.f, s2 = 0.f;
#pragma unroll
  for (int c = 0; c < 8; ++c) {
    float t = row[threadIdx.x + c * 256];
    v[c] = t; s += t; s2 += t * t;
  }
  s = block_sum(s, sm4);
  s2 = block_sum(s2, sm4);
  float mean = s * (1.f / Dh);
  float rstd = rsqrtf(s2 * (1.f / Dh) - mean * mean + LNEPS);
#pragma unroll
  for (int c = 0; c < 8; ++c) {
    int o = threadIdx.x + c * 256;
    out[r * Dh + o] = __float2bfloat16((v[c] - mean) * rstd * g[o] + b[o]);
  }
}

// outbd[b*D+d] += (1/S) * sum over an s-chunk of in[b,s,d]
__global__ __launch_bounds__(256) void meanrow_kernel(const bf16* __restrict__ in,
                                                      float* __restrict__ outbd) {
  int gid = blockIdx.x * 256 + threadIdx.x;
  int s0 = blockIdx.y * 128;
  long base = ((long)(gid >> 11) * Sh + s0) * Dh + (gid & 2047);
  float s = 0.f;
  for (int t = 0; t < 128; ++t) s += __bfloat162float(in[base + (long)t * Dh]);
  atomicAdd(&outbd[gid], s * (1.f / Sh));
}

// Per (n,i): LN prc row, add proto_w; n<3: dot with ctx -> routing; n==3: store ps3
__global__ __launch_bounds__(256) void route_kernel(
    const float* __restrict__ prc, const float* __restrict__ proto_w,
    const float* __restrict__ pln_g, const float* __restrict__ pln_b,
    const float* __restrict__ gate, const float* __restrict__ ctx,
    float* __restrict__ routing, float* __restrict__ ps3) {
  __shared__ float sm4[4];
  int i = blockIdx.x, n = blockIdx.y;
  long rb = ((long)n * Dh + i) * Dh;
  float v[8];
  float s = 0.f, s2 = 0.f;
#pragma unroll
  for (int c = 0; c < 8; ++c) {
    float t = prc[rb + threadIdx.x + c * 256];
    v[c] = t; s += t; s2 += t * t;
  }
  s = block_sum(s, sm4);
  s2 = block_sum(s2, sm4);
  float mean = s * (1.f / Dh);
  float rstd = rsqrtf(s2 * (1.f / Dh) - mean * mean + LNEPS);
  if (n == 3) {
#pragma unroll
    for (int c = 0; c < 8; ++c) {
      int o = threadIdx.x + c * 256;
      float ps = proto_w[rb + o] + (v[c] - mean) * rstd * pln_g[3 * Dh + o] + pln_b[3 * Dh + o];
      ps3[(long)i * Dh + o] = ps;
    }
  } else {
    float acc[4] = {0.f, 0.f, 0.f, 0.f};
#pragma unroll
    for (int c = 0; c < 8; ++c) {
      int o = threadIdx.x + c * 256;
      float ps = proto_w[rb + o] + (v[c] - mean) * rstd * pln_g[n * Dh + o] + pln_b[n * Dh + o];
#pragma unroll
      for (int b = 0; b < 4; ++b) acc[b] += ps * ctx[b * Dh + o];
    }
    for (int b = 0; b < 4; ++b) {
      float r = block_sum(acc[b], sm4);
      if (threadIdx.x == 0)
        routing[(n * 4 + b) * Dh + i] = r * INV_SQRT_D + gate[n * Dh + i];
    }
  }
}

__global__ __launch_bounds__(256) void route_o_kernel(
    const float* __restrict__ ps3, const float* __restrict__ ctxo,
    const float* __restrict__ gate, float* __restrict__ routing) {
  __shared__ float sm4[4];
  int i = blockIdx.x;
  float acc[4] = {0.f, 0.f, 0.f, 0.f};
#pragma unroll
  for (int c = 0; c < 8; ++c) {
    int o = threadIdx.x + c * 256;
    float p = ps3[(long)i * Dh + o];
#pragma unroll
    for (int b = 0; b < 4; ++b) acc[b] += p * ctxo[b * Dh + o];
  }
  for (int b = 0; b < 4; ++b) {
    float r = block_sum(acc[b], sm4);
    if (threadIdx.x == 0)
      routing[(12 + b) * Dh + i] = r * INV_SQRT_D + gate[3 * Dh + i];
  }
}

__global__ __launch_bounds__(256) void masnorm_kernel(const float* __restrict__ rin,
                                                      float* __restrict__ gout) {
  __shared__ float sm4[4];
  long r = blockIdx.x;
  float m = 0.f;
#pragma unroll
  for (int c = 0; c < 8; ++c)
    m = fmaxf(m, fabsf(rin[r * Dh + threadIdx.x + c * 256]));
  m = block_max(m, sm4);
  float inv = 1.f / (m + 1e-9f);
#pragma unroll
  for (int c = 0; c < 8; ++c) {
    int o = threadIdx.x + c * 256;
    gout[r * Dh + o] = rin[r * Dh + o] * inv;
  }
}

__global__ __launch_bounds__(256) void rope_table_kernel(float* __restrict__ cosT,
                                                         float* __restrict__ sinT) {
  int idx = blockIdx.x * 256 + threadIdx.x;
  int t = idx >> 10, f = idx & 1023;
  float inv_freq = expf(-(float)f * (9.210340371976184f / 1024.f));
  float ang = (float)t * inv_freq;
  cosT[idx] = cosf(ang);
  sinT[idx] = sinf(ang);
}

__global__ __launch_bounds__(256) void rope_kernel(bf16* __restrict__ q, bf16* __restrict__ k,
    const int* __restrict__ pos, const float* __restrict__ cosT,
    const float* __restrict__ sinT) {
  long r = blockIdx.x;
  int s = (int)(r & (Sh - 1));
  int p = pos[s];
#pragma unroll
  for (int c = 0; c < 4; ++c) {
    int t = threadIdx.x + c * 256;
    float cv = cosT[(long)p * HALF + t];
    float sv = sinT[(long)p * HALF + t];
    long i1 = r * Dh + t, i2 = i1 + HALF;
    float q1 = __bfloat162float(q[i1]), q2 = __bfloat162float(q[i2]);
    q[i1] = __float2bfloat16(q1 * cv - q2 * sv);
    q[i2] = __float2bfloat16(q2 * cv + q1 * sv);
    float k1 = __bfloat162float(k[i1]), k2 = __bfloat162float(k[i2]);
    k[i1] = __float2bfloat16(k1 * cv - k2 * sv);
    k[i2] = __float2bfloat16(k2 * cv + k1 * sv);
  }
}

// causal row softmax: read f32 scores (k<=q), write bf16 probs, zero-fill row
__global__ __launch_bounds__(256) void softmax_kernel(const float* __restrict__ scores,
                                                      bf16* __restrict__ probs) {
  __shared__ float buf[Sh];
  __shared__ float sm4[4];
  long r = blockIdx.x;
  int qi = (int)(r & (Sh - 1));
  const float* row = scores + r * (long)Sh;
  bf16* prow = probs + r * (long)Sh;
  int n = qi + 1;
  float m = -3.0e38f;
  for (int o = threadIdx.x; o < n; o += 256) {
    float x = row[o]; buf[o] = x; m = fmaxf(m, x);
  }
  m = block_max(m, sm4);
  float s = 0.f;
  for (int o = threadIdx.x; o < n; o += 256) {
    float e = __expf(buf[o] - m); buf[o] = e; s += e;
  }
  s = block_sum(s, sm4);
  float inv = 1.f / s;
  for (int o = threadIdx.x; o < n; o += 256) prow[o] = __float2bfloat16(buf[o] * inv);
  for (int o = n + (int)threadIdx.x; o < Sh; o += 256) prow[o] = __float2bfloat16(0.f);
}

extern "C" void kernel_launch(void* const* d_in, const int* in_sizes, int n_in,
                              void* d_out, int out_size, void* d_ws, size_t ws_size,
                              hipStream_t stream) {
  const float* x       = (const float*)d_in[0];
  const int*   pos     = (const int*)d_in[1];
  const float* ln1_g   = (const float*)d_in[2];
  const float* ln1_b   = (const float*)d_in[3];
  const float* mu_w    = (const float*)d_in[4];
  const float* mu_b    = (const float*)d_in[5];
  const float* proto_w = (const float*)d_in[6];
  const float* gate    = (const float*)d_in[7];
  const float* pt_w    = (const float*)d_in[8];
  const float* pln_g   = (const float*)d_in[9];
  const float* pln_b   = (const float*)d_in[10];
  const float* incoming= (const float*)d_in[11];

  // workspace layout (~302 MB); scores f32 lives in d_out (dead until o-proj)
  char* w = (char*)d_ws;
  const long BF = 33554432L;  // bytes of one bf16 [8192][2048]
  bf16*  ln1    = (bf16*)(w);
  bf16*  qb     = (bf16*)(w + BF);
  bf16*  kb     = (bf16*)(w + 2 * BF);
  bf16*  vb     = (bf16*)(w + 3 * BF);
  bf16*  attn   = (bf16*)(w + 4 * BF);
  bf16*  mu_wb  = (bf16*)(w + 5 * BF);         // [4][D][D] bf16
  bf16*  ptw_b  = (bf16*)(w + 6 * BF);         // aliased: later vT [4][D][S]
  bf16*  vT     = ptw_b;
  bf16*  inc_b  = (bf16*)(w + 7 * BF);         // aliased: later probs [4][S][S]
  bf16*  probs  = inc_b;
  float* ps3    = (float*)(w + 8 * BF);                 // [2048][2048] f32
  float* cosT   = (float*)(w + 8 * BF + 16777216L);
  float* sinT   = cosT + (long)Sh * HALF;
  float* ctx    = sinT + (long)Sh * HALF;               // [4][2048]
  float* ctxo   = ctx + Bh * Dh;
  float* routing= ctxo + Bh * Dh;                       // [16][2048]
  float* gating = routing + 16 * Dh;                    // [16][2048]
  float* scores = (float*)d_out;                        // f32 [4][2048][2048]

  const long DD4 = 4L * Dh * Dh;

  hipMemsetAsync(ctx, 0, 2L * Bh * Dh * sizeof(float), stream);

  rope_table_kernel<<<(Sh * HALF) / 256, 256, 0, stream>>>(cosT, sinT);
  cvt3_kernel<<<dim3(DD4 / 1024, 3), 256, 0, stream>>>(
      mu_w, incoming, pt_w, mu_wb, inc_b, ptw_b, DD4);
  ln1_kernel<<<NROW, 256, 0, stream>>>(x, ln1_g, ln1_b, ln1);
  meanrow_kernel<<<dim3(32, 16), 256, 0, stream>>>(ln1, ctx);
  // prc[n] = incoming[n] @ pt_w[n]^T  -> scores (f32, in d_out)
  pgemm<0><<<dim3(8, 8, 4), 512, 0, stream>>>(
      inc_b, ptw_b, scores, Dh, Dh, Dh, Dh,
      (long)Dh * Dh, (long)Dh * Dh, (long)Dh * Dh, nullptr, nullptr, nullptr);
  route_kernel<<<dim3(Dh, 4), 256, 0, stream>>>(scores, proto_w, pln_g, pln_b,
                                                gate, ctx, routing, ps3);
  masnorm_kernel<<<12, 256, 0, stream>>>(routing, gating);
  // q/k/v = gating * silu(ln1 @ mu_w[n]^T + mu_b[n])
  pgemm<1><<<dim3(32, 8, 3), 512, 0, stream>>>(
      ln1, mu_wb, qb, Dh, Dh, Dh, Dh,
      0L, (long)Dh * Dh, (long)NROW * Dh, mu_b, gating, nullptr);
  rope_kernel<<<NROW, 256, 0, stream>>>(qb, kb, pos, cosT, sinT);
  // scores = q @ k^T * inv_sqrt_d (causal blocks only)
  pgemm<2><<<dim3(8, 8, 4), 512, 0, stream>>>(
      qb, kb, scores, Sh, Dh, Dh, Dh,
      (long)Sh * Dh, (long)Sh * Dh, (long)Sh * Sh, nullptr, nullptr, nullptr);
  softmax_kernel<<<Bh * Sh, 256, 0, stream>>>(scores, probs);
  transpose_kernel<<<dim3(32, 32, 4), 256, 0, stream>>>(vb, vT);
  // attn = probs @ vT^T  (balanced BM=128 causal kernel)
  pgemm_h<<<512, 512, 0, stream>>>(
      probs, vT, attn, Dh, Sh, Sh,
      (long)Sh * Sh, (long)Dh * Sh, (long)Sh * Dh);
  meanrow_kernel<<<dim3(32, 16), 256, 0, stream>>>(attn, ctxo);
  route_o_kernel<<<Dh, 256, 0, stream>>>(ps3, ctxo, gate, routing);
  masnorm_kernel<<<4, 256, 0, stream>>>(routing + 12 * Dh, gating + 12 * Dh);
  // out = x + gating_o * silu(attn @ mu_w[3]^T + mu_b[3])
  pgemm<4><<<dim3(32, 8, 1), 512, 0, stream>>>(
      attn, mu_wb + 3L * Dh * Dh, d_out, Dh, Dh, Dh, Dh,
      0L, 0L, 0L, mu_b + 3 * Dh, gating + 12 * Dh, x);
}